// Round 10
// baseline (449.870 us; speedup 1.0000x reference)
//
#include <hip/hip_runtime.h>
#include <hip/hip_bf16.h>

typedef __attribute__((ext_vector_type(8))) short bf16x8;
typedef __attribute__((ext_vector_type(4))) float floatx4;

#define B_ 32
#define S_ 512
#define H_ 512
#define M_ (B_*S_)       // 16384 rows
#define K_ 512
#define N_ 1024          // 2H

// async global->LDS, 16B per lane, LDS dest = wave-uniform base + lane*16
__device__ __forceinline__ void gload_lds16(const void* g, void* l) {
  __builtin_amdgcn_global_load_lds(
      (const __attribute__((address_space(1))) void*)g,
      (__attribute__((address_space(3))) void*)l, 16, 0, 0);
}

// ---------------- fp32 -> bf16 weight convert (both W tensors, one launch) ----
__global__ void cvt2_kernel(const float* __restrict__ s0, const float* __restrict__ s1,
                            __hip_bfloat16* __restrict__ d0, __hip_bfloat16* __restrict__ d1) {
  int t = blockIdx.x * 256 + threadIdx.x;      // [0, 1048576)
  const float* src;
  __hip_bfloat16* dst;
  int i;
  if (t < 524288) { src = s0; dst = d0; i = t; }
  else            { src = s1; dst = d1; i = t - 524288; }
  float4 v = *(const float4*)(src + (size_t)i * 4);
  union { ushort4 u; __hip_bfloat16 h[4]; } pk;
  pk.h[0] = __float2bfloat16(v.x);
  pk.h[1] = __float2bfloat16(v.y);
  pk.h[2] = __float2bfloat16(v.z);
  pk.h[3] = __float2bfloat16(v.w);
  *(ushort4*)((unsigned short*)dst + (size_t)i * 4) = pk.u;
}

// ---------------- window conv (both dirs), writes bf16 x only ----------------
__global__ void conv_kernel(const float* __restrict__ inf, const float* __restrict__ inb,
                            int instride,
                            const float* __restrict__ fpad, const float* __restrict__ bpad,
                            const float* __restrict__ fw, const float* __restrict__ bw,
                            __hip_bfloat16* __restrict__ xaf, __hip_bfloat16* __restrict__ xab) {
  int t = blockIdx.x * 256 + threadIdx.x;      // 0 .. M_*128-1
  int dir = blockIdx.y;
  int row = t >> 7;                            // 0..16383  (= b*S + s)
  int hv  = (t & 127) << 2;                    // h, float4-vectorized
  int s = row & (S_ - 1);
  float4 a = make_float4(0.f, 0.f, 0.f, 0.f);
  if (dir == 0) {
#pragma unroll
    for (int k = 0; k < 5; ++k) {
      float w = fw[k];
      const float* src = (s + k < 4) ? (fpad + (size_t)(s + k) * H_ + hv)
                                     : (inf + (size_t)(row + k - 4) * instride + hv);
      float4 v = *(const float4*)src;
      a.x += w * v.x; a.y += w * v.y; a.z += w * v.z; a.w += w * v.w;
    }
  } else {
#pragma unroll
    for (int k = 0; k < 5; ++k) {
      float w = bw[k];
      const float* src = (s + k < S_) ? (inb + (size_t)(row + k) * instride + hv)
                                      : (bpad + (size_t)(s + k - S_) * H_ + hv);
      float4 v = *(const float4*)src;
      a.x += w * v.x; a.y += w * v.y; a.z += w * v.z; a.w += w * v.w;
    }
  }
  __hip_bfloat16* xa = dir ? xab : xaf;
  union { ushort4 u; __hip_bfloat16 h[4]; } pk;
  pk.h[0] = __float2bfloat16(a.x);
  pk.h[1] = __float2bfloat16(a.y);
  pk.h[2] = __float2bfloat16(a.z);
  pk.h[3] = __float2bfloat16(a.w);
  *(ushort4*)((unsigned short*)xa + (size_t)row * H_ + hv) = pk.u;
}

// ---------------- fused highway GEMM: persistent-W, A-only streaming ---------
// NEW mechanism (r9 proved 128KB+ dynamic LDS works on this harness): stage the
// block's ENTIRE W panel (128 proj rows x K=512 bf16 = 128KB) into LDS ONCE,
// then the K-loop streams only A (BK=32, 2x16KB dbuf). LDS = 160KB total.
// Eliminates per-step B staging (r3: 16KB/step) from the barrier drain — every
// prior variant (r3-r9) re-staged W each step and all plateaued ~60us/dispatch.
// Each block processes TWO 256-row A-panels sequentially reusing resident W
// (amortizes W prologue; keeps 512-block grid = 2 rounds over 256 CUs).
// 512 thr (8 waves, 4M x 2N): wave = 64 rows x 64 proj cols (32 out cols,
// nl+gate paired) -> acc 4x4 floatx4 = 64 VGPR.
// W LDS layout: row r in [0,128): wn_=r>>6, rr=r&63; rr<32 -> nonlin col
// (h0+wn_*32+rr), else gate (512+h0+wn_*32+rr-32) — wave wn's 4 j-subtiles are
// 2 nl + 2 gate of the SAME out cols. Swizzle: 16B slot s of row r holds global
// k-chunk s^(r&7); stored via per-lane source permute (one row per gload_lds,
// r&7 == wave); read slot (kp*4+quad)^(l16&7) -> exactly 2 lanes/bank (free).
// A path (staging swizzle/read/snapshot): r3-verbatim (verified rounds 3-9).
// Epilogue stages output tile through the A region -> full-line HBM writes.
__global__ __launch_bounds__(512, 2)
void hw_gemm(const __hip_bfloat16* __restrict__ Af, const __hip_bfloat16* __restrict__ Ab,
             const __hip_bfloat16* __restrict__ Wf, const __hip_bfloat16* __restrict__ Wb,
             const float* __restrict__ biasf, const float* __restrict__ biasb,
             __hip_bfloat16* __restrict__ Anf, __hip_bfloat16* __restrict__ Anb,
             float* __restrict__ outp, int final_mode) {
  extern __shared__ __align__(16) char smem[];  // 163840: W 128KB | A dbuf 2x16KB

  const int tid = threadIdx.x;
  const int lane = tid & 63, wave = tid >> 6;    // 8 waves
  const int wm = wave >> 1, wn = wave & 1;       // 4M x 2N
  const int quad = lane >> 4, l16 = lane & 15;
  const int dir = blockIdx.z;

  const int n = blockIdx.x;                      // [0,256)
  const int by = n & 31, bx = n >> 5;            // bx in [0,8); A-panel siblings share n&7
  const int h0 = bx * 64;                        // out-col base (64 cols/block)

  const __hip_bfloat16* A = dir ? Ab : Af;
  const __hip_bfloat16* Wm = dir ? Wb : Wf;
  const float* bias = dir ? biasb : biasf;
  __hip_bfloat16* An = dir ? Anb : Anf;

  char* Abase = smem + 131072;                   // A dbuf region (2 x 16KB)

  // ---- prologue: stage entire W panel (128 rows x 512 k) once ----
  // iteration it stages rows it*8 + wave; lane l stages slot l of that row,
  // which must hold global chunk l ^ (r&7) = l ^ wave.
#pragma unroll
  for (int it = 0; it < 16; ++it) {
    const int r = it * 8 + wave;
    const int wn_ = r >> 6, rr = r & 63;
    const int wrow = (rr < 32) ? (h0 + wn_ * 32 + rr)
                               : (512 + h0 + wn_ * 32 + (rr - 32));
    gload_lds16(Wm + (size_t)wrow * K_ + ((lane ^ wave) << 3),
                smem + it * 8192 + wave * 1024);
  }

  const int srow = lane >> 2;                    // A staging: row within 16-row chunk
  const int skk  = (((lane & 3) ^ ((lane >> 3) & 3)) << 3);  // swizzled src k offset
  const int key  = (l16 >> 1) & 3;               // A read-side swizzle key
  const int xkp  = bx * 2 + wn;                  // K-tile holding this wave's x cols

  float bnl[2], bgt[2];
#pragma unroll
  for (int j = 0; j < 2; ++j) {
    const int c = h0 + wn * 32 + j * 16 + l16;
    bnl[j] = bias[c];
    bgt[j] = bias[512 + c];
  }

  const __hip_bfloat16* lW = (const __hip_bfloat16*)smem;

  for (int half = 0; half < 2; ++half) {
    const int m0 = by * 512 + half * 256;

    // A staging base pointers for this half (r3-verbatim geometry)
    const __hip_bfloat16* aptr[2];
#pragma unroll
    for (int c = 0; c < 2; ++c) {
      const int chunk = wave * 2 + c;            // [0,16): rows chunk*16..+16
      aptr[c] = A + (size_t)(m0 + chunk * 16 + srow) * K_ + skk;
    }

    floatx4 acc[4][4];   // [m][j: 0,1 nonlin  2,3 gate]
#pragma unroll
    for (int i = 0; i < 4; ++i)
#pragma unroll
      for (int j = 0; j < 4; ++j) acc[i][j] = (floatx4){0.f, 0.f, 0.f, 0.f};

    // stage A K-tile 0 into buffer 0 (W loads also drain at this barrier on half 0)
#pragma unroll
    for (int c = 0; c < 2; ++c)
      gload_lds16(aptr[c], Abase + (wave * 2 + c) * 1024);
    __syncthreads();

    unsigned int xsp[4][2][2];   // residual x, bf16-packed row pairs (static idx)
    int cur = 0;
    for (int kp = 0; kp < 16; ++kp) {
      const __hip_bfloat16* cA = (const __hip_bfloat16*)(Abase + cur * 16384);
      // issue next A-tile into the other buffer (lands at end-of-iter barrier)
      if (kp < 15) {
        char* nb = Abase + (cur ^ 1) * 16384;
        const int kb = (kp + 1) * 32;
#pragma unroll
        for (int c = 0; c < 2; ++c)
          gload_lds16(aptr[c] + kb, nb + (wave * 2 + c) * 1024);
      }
      if (kp == xkp) {           // snapshot this wave's 32 x cols (r3 formula)
        const unsigned short* pA = (const unsigned short*)cA;
#pragma unroll
        for (int i = 0; i < 4; ++i)
#pragma unroll
          for (int jj = 0; jj < 2; ++jj)
#pragma unroll
            for (int rh = 0; rh < 2; ++rh) {
              const int ra0 = wm * 64 + i * 16 + quad * 4 + rh * 2;
              const int ra1 = ra0 + 1;
              const int c2 = jj * 16 + l16;
              unsigned int lo = pA[ra0 * 32 + ((((c2 >> 3) ^ ((ra0 >> 1) & 3)) << 3) | (c2 & 7))];
              unsigned int hi = pA[ra1 * 32 + ((((c2 >> 3) ^ ((ra1 >> 1) & 3)) << 3) | (c2 & 7))];
              xsp[i][jj][rh] = lo | (hi << 16);
            }
      }
      // compute: av from A dbuf (r3 read), bv from persistent W (no re-stage)
      bf16x8 av[4], bv[4];
#pragma unroll
      for (int i = 0; i < 4; ++i) {
        const int ra = wm * 64 + i * 16 + l16;
        av[i] = *(const bf16x8*)&cA[ra * 32 + ((quad ^ key) << 3)];
      }
#pragma unroll
      for (int j = 0; j < 4; ++j) {
        const int rb = wn * 64 + j * 16 + l16;
        const int slot = (kp * 4 + quad) ^ (l16 & 7);
        bv[j] = *(const bf16x8*)&lW[(size_t)rb * 512 + slot * 8];
      }
#pragma unroll
      for (int i = 0; i < 4; ++i)
#pragma unroll
        for (int j = 0; j < 4; ++j)
          acc[i][j] = __builtin_amdgcn_mfma_f32_16x16x32_bf16(av[i], bv[j], acc[i][j], 0, 0, 0);

      __syncthreads();   // drains vmcnt (next A-tile staged) + reads of cur done
      cur ^= 1;
    }
    // A region (32KB) is dead -> epilogue staging buffer (W region stays live!)

    if (final_mode) {
      // fp32 [256][32] per wn-pass = 32KB in A region; full-line (128B/row) stores
      float* ft = (float*)Abase;
#pragma unroll
      for (int p = 0; p < 2; ++p) {
        if (wn == p) {
#pragma unroll
          for (int i = 0; i < 4; ++i)
#pragma unroll
            for (int r = 0; r < 4; ++r) {
              const int rl = wm * 64 + i * 16 + quad * 4 + r;
#pragma unroll
              for (int j = 0; j < 2; ++j) {
                float pn = acc[i][j][r] + bnl[j];
                float pg = acc[i][j + 2][r] + bgt[j];
                float g = 1.f / (1.f + __expf(-pg));
                unsigned int u = xsp[i][j][r >> 1];
                unsigned int bits = (r & 1) ? (u >> 16) : (u & 0xffffu);
                float xo = __uint_as_float(bits << 16);
                ft[rl * 32 + j * 16 + l16] = g * xo + (1.f - g) * fmaxf(pn, 0.f);
              }
            }
        }
        __syncthreads();
#pragma unroll
        for (int q = 0; q < 4; ++q) {
          const int rl = q * 64 + (tid >> 3);
          const int cc = (tid & 7) * 4;
          float4 v = *(const float4*)&ft[rl * 32 + cc];
          *(float4*)&outp[(size_t)(m0 + rl) * N_ + dir * H_ + h0 + p * 32 + cc] = v;
        }
        __syncthreads();
      }
    } else {
      // bf16 [256][64] = 32KB in A region; full-line (128B/row) stores
      __hip_bfloat16* bt = (__hip_bfloat16*)Abase;
#pragma unroll
      for (int i = 0; i < 4; ++i)
#pragma unroll
        for (int r = 0; r < 4; ++r) {
          const int rl = wm * 64 + i * 16 + quad * 4 + r;
#pragma unroll
          for (int j = 0; j < 2; ++j) {
            float pn = acc[i][j][r] + bnl[j];
            float pg = acc[i][j + 2][r] + bgt[j];
            float g = 1.f / (1.f + __expf(-pg));
            unsigned int u = xsp[i][j][r >> 1];
            unsigned int bits = (r & 1) ? (u >> 16) : (u & 0xffffu);
            float xo = __uint_as_float(bits << 16);
            bt[rl * 64 + wn * 32 + j * 16 + l16] =
                __float2bfloat16(g * xo + (1.f - g) * fmaxf(pn, 0.f));
          }
        }
      __syncthreads();
      const unsigned short* src = (const unsigned short*)Abase;
#pragma unroll
      for (int p = 0; p < 4; ++p) {
        const int rl = p * 64 + (tid >> 3);
        const int cc = (tid & 7) * 8;             // 8 bf16 = 16B per lane
        int4 v = *(const int4*)(src + rl * 64 + cc);
        *(int4*)((unsigned short*)An + (size_t)(m0 + rl) * H_ + h0 + cc) = v;
      }
      __syncthreads();   // epilogue staging dead before next half re-stages A
    }
  }
}

extern "C" void kernel_launch(void* const* d_in, const int* in_sizes, int n_in,
                              void* d_out, int out_size, void* d_ws, size_t ws_size,
                              hipStream_t stream) {
  const float* inputs   = (const float*)d_in[0];
  // d_in[1] = masks (unused by reference)
  const float* fwd_pads = (const float*)d_in[2];
  const float* bwd_pads = (const float*)d_in[3];
  const float* fwd_ws_p = (const float*)d_in[4];
  const float* bwd_ws_p = (const float*)d_in[5];
  const float* fwd_hw_W = (const float*)d_in[6];
  const float* fwd_hw_b = (const float*)d_in[7];
  const float* bwd_hw_W = (const float*)d_in[8];
  const float* bwd_hw_b = (const float*)d_in[9];
  float* out = (float*)d_out;

  // one-time opt-in to 160KB dynamic LDS (host-side attribute; proven working
  // at 128KB in round 9; AITER uses 160KB workgroups on gfx950).
  static int attr_done = 0;
  if (!attr_done) {
    (void)hipFuncSetAttribute((const void*)hw_gemm,
                              hipFuncAttributeMaxDynamicSharedMemorySize, 163840);
    attr_done = 1;
  }

  char* ws = (char*)d_ws;
  size_t off = 0;
  __hip_bfloat16* Wbf = (__hip_bfloat16*)(ws + off); off += (size_t)4194304 * 2;  // 8 matrices [1024,512]
  __hip_bfloat16* xa0f = (__hip_bfloat16*)(ws + off); off += (size_t)M_ * H_ * 2;
  __hip_bfloat16* xa0b = (__hip_bfloat16*)(ws + off); off += (size_t)M_ * H_ * 2;
  __hip_bfloat16* xa1f = (__hip_bfloat16*)(ws + off); off += (size_t)M_ * H_ * 2;
  __hip_bfloat16* xa1b = (__hip_bfloat16*)(ws + off); off += (size_t)M_ * H_ * 2;
  // total ~75 MiB

  // weights -> bf16 (fwd at 0, bwd at +2097152 elements), single launch
  cvt2_kernel<<<4096, 256, 0, stream>>>(fwd_hw_W, bwd_hw_W, Wbf, Wbf + (size_t)2097152);

  for (int l = 0; l < 2; ++l) {
    const float *inf, *inb;
    int instride;
    if (l == 0) { inf = inputs; inb = inputs; instride = H_; }
    else        { inf = out;    inb = out + H_; instride = N_; }  // read layer-0 output
    conv_kernel<<<dim3(8192, 2), 256, 0, stream>>>(
        inf, inb, instride,
        fwd_pads + (size_t)l * 4 * H_, bwd_pads + (size_t)l * 4 * H_,
        fwd_ws_p + l * 5, bwd_ws_p + l * 5,
        xa0f, xa0b);

    // highway iter 0 (writes bf16 x ping)
    hw_gemm<<<dim3(256, 1, 2), 512, 163840, stream>>>(
        xa0f, xa0b,
        Wbf + (size_t)(l * 2) * 524288, Wbf + (size_t)2097152 + (size_t)(l * 2) * 524288,
        fwd_hw_b + (l * 2) * 1024, bwd_hw_b + (l * 2) * 1024,
        xa1f, xa1b, nullptr, 0);

    // highway iter 1 (final: writes d_out[l])
    hw_gemm<<<dim3(256, 1, 2), 512, 163840, stream>>>(
        xa1f, xa1b,
        Wbf + (size_t)(l * 2 + 1) * 524288, Wbf + (size_t)2097152 + (size_t)(l * 2 + 1) * 524288,
        fwd_hw_b + (l * 2 + 1) * 1024, bwd_hw_b + (l * 2 + 1) * 1024,
        nullptr, nullptr, out + (size_t)l * M_ * N_, 1);
  }
}

// Round 11
// 448.662 us; speedup vs baseline: 1.0027x; 1.0027x over previous
//
#include <hip/hip_runtime.h>
#include <hip/hip_bf16.h>

typedef __attribute__((ext_vector_type(8))) short bf16x8;
typedef __attribute__((ext_vector_type(4))) float floatx4;

#define B_ 32
#define S_ 512
#define H_ 512
#define M_ (B_*S_)       // 16384 rows
#define K_ 512
#define N_ 1024          // 2H

// async global->LDS, 16B per lane, LDS dest = wave-uniform base + lane*16
__device__ __forceinline__ void gload_lds16(const void* g, void* l) {
  __builtin_amdgcn_global_load_lds(
      (const __attribute__((address_space(1))) void*)g,
      (__attribute__((address_space(3))) void*)l, 16, 0, 0);
}

// ---------------- fp32 -> bf16 weight convert (both W tensors, one launch) ----
__global__ void cvt2_kernel(const float* __restrict__ s0, const float* __restrict__ s1,
                            __hip_bfloat16* __restrict__ d0, __hip_bfloat16* __restrict__ d1) {
  int t = blockIdx.x * 256 + threadIdx.x;      // [0, 1048576)
  const float* src;
  __hip_bfloat16* dst;
  int i;
  if (t < 524288) { src = s0; dst = d0; i = t; }
  else            { src = s1; dst = d1; i = t - 524288; }
  float4 v = *(const float4*)(src + (size_t)i * 4);
  union { ushort4 u; __hip_bfloat16 h[4]; } pk;
  pk.h[0] = __float2bfloat16(v.x);
  pk.h[1] = __float2bfloat16(v.y);
  pk.h[2] = __float2bfloat16(v.z);
  pk.h[3] = __float2bfloat16(v.w);
  *(ushort4*)((unsigned short*)dst + (size_t)i * 4) = pk.u;
}

// ---------------- window conv (both dirs), writes bf16 x only ----------------
__global__ void conv_kernel(const float* __restrict__ inf, const float* __restrict__ inb,
                            int instride,
                            const float* __restrict__ fpad, const float* __restrict__ bpad,
                            const float* __restrict__ fw, const float* __restrict__ bw,
                            __hip_bfloat16* __restrict__ xaf, __hip_bfloat16* __restrict__ xab) {
  int t = blockIdx.x * 256 + threadIdx.x;      // 0 .. M_*128-1
  int dir = blockIdx.y;
  int row = t >> 7;                            // 0..16383  (= b*S + s)
  int hv  = (t & 127) << 2;                    // h, float4-vectorized
  int s = row & (S_ - 1);
  float4 a = make_float4(0.f, 0.f, 0.f, 0.f);
  if (dir == 0) {
#pragma unroll
    for (int k = 0; k < 5; ++k) {
      float w = fw[k];
      const float* src = (s + k < 4) ? (fpad + (size_t)(s + k) * H_ + hv)
                                     : (inf + (size_t)(row + k - 4) * instride + hv);
      float4 v = *(const float4*)src;
      a.x += w * v.x; a.y += w * v.y; a.z += w * v.z; a.w += w * v.w;
    }
  } else {
#pragma unroll
    for (int k = 0; k < 5; ++k) {
      float w = bw[k];
      const float* src = (s + k < S_) ? (inb + (size_t)(row + k) * instride + hv)
                                      : (bpad + (size_t)(s + k - S_) * H_ + hv);
      float4 v = *(const float4*)src;
      a.x += w * v.x; a.y += w * v.y; a.z += w * v.z; a.w += w * v.w;
    }
  }
  __hip_bfloat16* xa = dir ? xab : xaf;
  union { ushort4 u; __hip_bfloat16 h[4]; } pk;
  pk.h[0] = __float2bfloat16(a.x);
  pk.h[1] = __float2bfloat16(a.y);
  pk.h[2] = __float2bfloat16(a.z);
  pk.h[3] = __float2bfloat16(a.w);
  *(ushort4*)((unsigned short*)xa + (size_t)row * H_ + hv) = pk.u;
}

// ------- fused highway GEMM: fine-phased 4-slot ring, counted vmcnt ---------
// Geometry/formulas = r3 (session best, 420.7us): 512 thr (8 waves, 4M x 2N),
// tile 256 rows x 256 proj cols, BK=32, swizzle key=(row>>1)&3, B-row remap,
// LDS-staged epilogue. ONLY the K-loop schedule changes (the one axis r4-r10
// never actually touched: fine interleave — m196/m230's isolated lever):
//  - 4-slot LDS ring (4 x 32KB = 128KB dynamic; r9 proved dynamic LDS works):
//    tiles kp..kp+2 resident, kp+3 staging into the slot freed by kp-1.
//    (2-buffer layouts structurally cannot stage >1 tile ahead: slot conflict.)
//  - 2 phases per K-tile: {ds_read subtile || stage 1 half-tile (2 gload_lds)
//    -> s_barrier -> setprio(1) 16 MFMA setprio(0) -> s_barrier}.
//    Phase 0: av[4]+bv[0..3] reads + A-half stage; phase 1: bv[4..7] + B-half.
//  - Counted boundary vmcnt, never 0 in main loop: at window end, vmcnt(8)
//    (= tiles kp+1,kp+2's 4+4 loads in flight; forces kp+1 landed). Wait is
//    BEFORE the window-end barrier -> all waves' loads confirmed before any
//    wave reads. Tail: vmcnt(4) entering tile 14, vmcnt(0) entering 15.
//    FIFO audit: stage of kp+3 issues during window kp; at end of window kp
//    the 8 newest per-thread loads are tiles kp+2,kp+3 -> vmcnt(8) forces
//    kp+1 landed. Slots disjoint mod 4 -> stage never touches a live slot.
__global__ __launch_bounds__(512, 2)
void hw_gemm(const __hip_bfloat16* __restrict__ Af, const __hip_bfloat16* __restrict__ Ab,
             const __hip_bfloat16* __restrict__ Wf, const __hip_bfloat16* __restrict__ Wb,
             const float* __restrict__ biasf, const float* __restrict__ biasb,
             __hip_bfloat16* __restrict__ Anf, __hip_bfloat16* __restrict__ Anb,
             float* __restrict__ outp, int final_mode) {
  extern __shared__ __align__(16) char smem[];  // 131072 = 4 slots x {A 16K | B 16K}

  const int tid = threadIdx.x;
  const int lane = tid & 63, wave = tid >> 6;    // 8 waves
  const int wm = wave >> 1, wn = wave & 1;       // 4M x 2N
  const int quad = lane >> 4, l16 = lane & 15;
  const int dir = blockIdx.z;

  const int n = blockIdx.x;                      // [0,256)
  const int by = n & 63, bx = n >> 6;            // h-siblings share (n&7) -> same XCD
  const int m0 = by * 256;
  const int h0 = bx * 128;                       // out-col base

  const __hip_bfloat16* A = dir ? Ab : Af;
  const __hip_bfloat16* Wm = dir ? Wb : Wf;
  const float* bias = dir ? biasb : biasf;
  __hip_bfloat16* An = dir ? Anb : Anf;

  floatx4 acc[4][8];   // [m][j: 0..3 nonlin, 4..7 gate]
#pragma unroll
  for (int i = 0; i < 4; ++i)
#pragma unroll
    for (int j = 0; j < 8; ++j) acc[i][j] = (floatx4){0.f, 0.f, 0.f, 0.f};

  const int srow = lane >> 2;                    // row within 16-row staging chunk
  const int skk  = (((lane & 3) ^ ((lane >> 3) & 3)) << 3);  // swizzled src k offset
  const int key  = (l16 >> 1) & 3;               // read-side swizzle key
  const int xkp0 = bx * 4 + wn * 2;              // K-tiles holding this wave's x cols
  const int xkp1 = xkp0 + 1;                     // (max 9 < 15: safely in-loop)

  // hoisted staging base pointers (2 A-chunks + 2 B-chunks per wave, 16 rows each)
  const __hip_bfloat16* aptr[2];
  const __hip_bfloat16* bptr[2];
#pragma unroll
  for (int c = 0; c < 2; ++c) {
    const int chunk = wave * 2 + c;              // [0,16): rows chunk*16..+16
    aptr[c] = A + (size_t)(m0 + chunk * 16 + srow) * K_ + skk;
    const int brow = chunk * 16 + srow;          // LDS B row
    const int wnp = brow >> 7, rr = brow & 127;  // wave-half, row within
    const int wrow = (rr < 64) ? (h0 + wnp * 64 + rr)                // nonlin W row
                               : (512 + h0 + wnp * 64 + (rr - 64));  // gate W row
    bptr[c] = Wm + (size_t)wrow * K_ + skk;
  }

  // prologue: stage K-tiles 0,1,2 into ring slots 0,1,2 (12 loads/thread)
#pragma unroll
  for (int tt = 0; tt < 3; ++tt)
#pragma unroll
    for (int c = 0; c < 2; ++c) {
      const int chunk = wave * 2 + c;
      gload_lds16(aptr[c] + tt * 32, smem + (tt << 15) + chunk * 1024);
      gload_lds16(bptr[c] + tt * 32, smem + (tt << 15) + 16384 + chunk * 1024);
    }
  asm volatile("s_waitcnt vmcnt(8)" ::: "memory");   // tile 0 landed; 1,2 in flight
  __builtin_amdgcn_s_barrier();

  unsigned int xsp[4][4][2];   // residual x, bf16-packed row pairs — static indices
  for (int kp = 0; kp < 16; ++kp) {
    const __hip_bfloat16* cA = (const __hip_bfloat16*)(smem + ((kp & 3) << 15));
    const __hip_bfloat16* cB = (const __hip_bfloat16*)(smem + ((kp & 3) << 15) + 16384);
    char* nb = smem + (((kp + 3) & 3) << 15);    // staging slot (= slot of kp-1, dead)
    const int kb = (kp + 3) * 32;

    // ===== phase 0: read av + bv[0..3]; stage A-half of tile kp+3 =====
    bf16x8 av[4], bv[4];
#pragma unroll
    for (int i = 0; i < 4; ++i) {
      const int ra = wm * 64 + i * 16 + l16;
      av[i] = *(const bf16x8*)&cA[ra * 32 + ((quad ^ key) << 3)];
    }
#pragma unroll
    for (int jj = 0; jj < 4; ++jj) {
      const int rb = wn * 128 + jj * 16 + l16;
      bv[jj] = *(const bf16x8*)&cB[rb * 32 + ((quad ^ key) << 3)];
    }
    if (kp == xkp0) {            // snapshot x cols [0,32) of this wave (j=0,1)
      const unsigned short* pA = (const unsigned short*)cA;
#pragma unroll
      for (int i = 0; i < 4; ++i)
#pragma unroll
        for (int jj = 0; jj < 2; ++jj)
#pragma unroll
          for (int rh = 0; rh < 2; ++rh) {
            const int ra0 = wm * 64 + i * 16 + quad * 4 + rh * 2;
            const int ra1 = ra0 + 1;
            const int c2 = jj * 16 + l16;
            unsigned int lo = pA[ra0 * 32 + ((((c2 >> 3) ^ ((ra0 >> 1) & 3)) << 3) | (c2 & 7))];
            unsigned int hi = pA[ra1 * 32 + ((((c2 >> 3) ^ ((ra1 >> 1) & 3)) << 3) | (c2 & 7))];
            xsp[i][jj][rh] = lo | (hi << 16);
          }
    }
    if (kp == xkp1) {            // snapshot x cols [32,64) (j=2,3)
      const unsigned short* pA = (const unsigned short*)cA;
#pragma unroll
      for (int i = 0; i < 4; ++i)
#pragma unroll
        for (int jj = 0; jj < 2; ++jj)
#pragma unroll
          for (int rh = 0; rh < 2; ++rh) {
            const int ra0 = wm * 64 + i * 16 + quad * 4 + rh * 2;
            const int ra1 = ra0 + 1;
            const int c2 = jj * 16 + l16;
            unsigned int lo = pA[ra0 * 32 + ((((c2 >> 3) ^ ((ra0 >> 1) & 3)) << 3) | (c2 & 7))];
            unsigned int hi = pA[ra1 * 32 + ((((c2 >> 3) ^ ((ra1 >> 1) & 3)) << 3) | (c2 & 7))];
            xsp[i][2 + jj][rh] = lo | (hi << 16);
          }
    }
    if (kp < 13) {
#pragma unroll
      for (int c = 0; c < 2; ++c)
        gload_lds16(aptr[c] + kb, nb + (wave * 2 + c) * 1024);
    }
    asm volatile("" ::: "memory");
    __builtin_amdgcn_s_barrier();
    __builtin_amdgcn_s_setprio(1);
#pragma unroll
    for (int i = 0; i < 4; ++i)
#pragma unroll
      for (int jj = 0; jj < 4; ++jj)
        acc[i][jj] = __builtin_amdgcn_mfma_f32_16x16x32_bf16(av[i], bv[jj], acc[i][jj], 0, 0, 0);
    __builtin_amdgcn_s_setprio(0);
    asm volatile("" ::: "memory");
    __builtin_amdgcn_s_barrier();

    // ===== phase 1: read bv[4..7] (av reused); stage B-half of tile kp+3 =====
#pragma unroll
    for (int jj = 0; jj < 4; ++jj) {
      const int rb = wn * 128 + (4 + jj) * 16 + l16;
      bv[jj] = *(const bf16x8*)&cB[rb * 32 + ((quad ^ key) << 3)];
    }
    if (kp < 13) {
#pragma unroll
      for (int c = 0; c < 2; ++c)
        gload_lds16(bptr[c] + kb, nb + 16384 + (wave * 2 + c) * 1024);
    }
    asm volatile("" ::: "memory");
    __builtin_amdgcn_s_barrier();
    __builtin_amdgcn_s_setprio(1);
#pragma unroll
    for (int i = 0; i < 4; ++i)
#pragma unroll
      for (int jj = 0; jj < 4; ++jj)
        acc[i][4 + jj] = __builtin_amdgcn_mfma_f32_16x16x32_bf16(av[i], bv[jj], acc[i][4 + jj], 0, 0, 0);
    __builtin_amdgcn_s_setprio(0);
    // boundary: ensure tile kp+1 landed before any wave reads it next window
    if (kp < 13)       asm volatile("s_waitcnt vmcnt(8)" ::: "memory");
    else if (kp == 13) asm volatile("s_waitcnt vmcnt(4)" ::: "memory");
    else if (kp == 14) asm volatile("s_waitcnt vmcnt(0)" ::: "memory");
    __builtin_amdgcn_s_barrier();
  }
  // all loads drained (vmcnt(0) entering tile 15); smem dead -> epilogue tile

  float bnl[4], bgt[4];
#pragma unroll
  for (int j = 0; j < 4; ++j) {
    const int c = h0 + wn * 64 + j * 16 + l16;
    bnl[j] = bias[c];
    bgt[j] = bias[512 + c];
  }

  if (final_mode) {
    // fp32 [256][64] per wn-half = 64KB; two passes, full-line (2x128B/row) stores
    float* ft = (float*)smem;
#pragma unroll
    for (int p = 0; p < 2; ++p) {
      if (wn == p) {
#pragma unroll
        for (int i = 0; i < 4; ++i)
#pragma unroll
          for (int r = 0; r < 4; ++r) {
            const int rl = wm * 64 + i * 16 + quad * 4 + r;
#pragma unroll
            for (int j = 0; j < 4; ++j) {
              float pn = acc[i][j][r] + bnl[j];
              float pg = acc[i][j + 4][r] + bgt[j];
              float g = 1.f / (1.f + __expf(-pg));
              unsigned int u = xsp[i][j][r >> 1];
              unsigned int bits = (r & 1) ? (u >> 16) : (u & 0xffffu);
              float xo = __uint_as_float(bits << 16);
              ft[rl * 64 + j * 16 + l16] = g * xo + (1.f - g) * fmaxf(pn, 0.f);
            }
          }
      }
      __syncthreads();
#pragma unroll
      for (int q = 0; q < 8; ++q) {
        const int rl = q * 32 + (tid >> 4);
        const int cc = (tid & 15) * 4;
        float4 v = *(const float4*)&ft[rl * 64 + cc];
        *(float4*)&outp[(size_t)(m0 + rl) * N_ + dir * H_ + h0 + p * 64 + cc] = v;
      }
      __syncthreads();
    }
  } else {
    // bf16 [256][128] = 64KB; one pass, full-line (2x128B/row) stores
    __hip_bfloat16* bt = (__hip_bfloat16*)smem;
#pragma unroll
    for (int i = 0; i < 4; ++i)
#pragma unroll
      for (int r = 0; r < 4; ++r) {
        const int rl = wm * 64 + i * 16 + quad * 4 + r;
#pragma unroll
        for (int j = 0; j < 4; ++j) {
          float pn = acc[i][j][r] + bnl[j];
          float pg = acc[i][j + 4][r] + bgt[j];
          float g = 1.f / (1.f + __expf(-pg));
          unsigned int u = xsp[i][j][r >> 1];
          unsigned int bits = (r & 1) ? (u >> 16) : (u & 0xffffu);
          float xo = __uint_as_float(bits << 16);
          bt[rl * 128 + wn * 64 + j * 16 + l16] =
              __float2bfloat16(g * xo + (1.f - g) * fmaxf(pn, 0.f));
        }
      }
    __syncthreads();
    const unsigned short* src = (const unsigned short*)smem;
#pragma unroll
    for (int p = 0; p < 8; ++p) {
      const int rl = p * 32 + (tid >> 4);
      const int cc = (tid & 15) * 8;             // 8 bf16 = 16B per lane
      int4 v = *(const int4*)(src + rl * 128 + cc);
      *(int4*)((unsigned short*)An + (size_t)(m0 + rl) * H_ + h0 + cc) = v;
    }
  }
}

extern "C" void kernel_launch(void* const* d_in, const int* in_sizes, int n_in,
                              void* d_out, int out_size, void* d_ws, size_t ws_size,
                              hipStream_t stream) {
  const float* inputs   = (const float*)d_in[0];
  // d_in[1] = masks (unused by reference)
  const float* fwd_pads = (const float*)d_in[2];
  const float* bwd_pads = (const float*)d_in[3];
  const float* fwd_ws_p = (const float*)d_in[4];
  const float* bwd_ws_p = (const float*)d_in[5];
  const float* fwd_hw_W = (const float*)d_in[6];
  const float* fwd_hw_b = (const float*)d_in[7];
  const float* bwd_hw_W = (const float*)d_in[8];
  const float* bwd_hw_b = (const float*)d_in[9];
  float* out = (float*)d_out;

  // one-time opt-in to 128KB dynamic LDS (host-side attribute; r9/r10-proven safe)
  static int attr_done = 0;
  if (!attr_done) {
    (void)hipFuncSetAttribute((const void*)hw_gemm,
                              hipFuncAttributeMaxDynamicSharedMemorySize, 131072);
    attr_done = 1;
  }

  char* ws = (char*)d_ws;
  size_t off = 0;
  __hip_bfloat16* Wbf = (__hip_bfloat16*)(ws + off); off += (size_t)4194304 * 2;  // 8 matrices [1024,512]
  __hip_bfloat16* xa0f = (__hip_bfloat16*)(ws + off); off += (size_t)M_ * H_ * 2;
  __hip_bfloat16* xa0b = (__hip_bfloat16*)(ws + off); off += (size_t)M_ * H_ * 2;
  __hip_bfloat16* xa1f = (__hip_bfloat16*)(ws + off); off += (size_t)M_ * H_ * 2;
  __hip_bfloat16* xa1b = (__hip_bfloat16*)(ws + off); off += (size_t)M_ * H_ * 2;
  // total ~75 MiB

  // weights -> bf16 (fwd at 0, bwd at +2097152 elements), single launch
  cvt2_kernel<<<4096, 256, 0, stream>>>(fwd_hw_W, bwd_hw_W, Wbf, Wbf + (size_t)2097152);

  for (int l = 0; l < 2; ++l) {
    const float *inf, *inb;
    int instride;
    if (l == 0) { inf = inputs; inb = inputs; instride = H_; }
    else        { inf = out;    inb = out + H_; instride = N_; }  // read layer-0 output
    conv_kernel<<<dim3(8192, 2), 256, 0, stream>>>(
        inf, inb, instride,
        fwd_pads + (size_t)l * 4 * H_, bwd_pads + (size_t)l * 4 * H_,
        fwd_ws_p + l * 5, bwd_ws_p + l * 5,
        xa0f, xa0b);

    // highway iter 0 (writes bf16 x ping)
    hw_gemm<<<dim3(256, 1, 2), 512, 131072, stream>>>(
        xa0f, xa0b,
        Wbf + (size_t)(l * 2) * 524288, Wbf + (size_t)2097152 + (size_t)(l * 2) * 524288,
        fwd_hw_b + (l * 2) * 1024, bwd_hw_b + (l * 2) * 1024,
        xa1f, xa1b, nullptr, 0);

    // highway iter 1 (final: writes d_out[l])
    hw_gemm<<<dim3(256, 1, 2), 512, 131072, stream>>>(
        xa1f, xa1b,
        Wbf + (size_t)(l * 2 + 1) * 524288, Wbf + (size_t)2097152 + (size_t)(l * 2 + 1) * 524288,
        fwd_hw_b + (l * 2 + 1) * 1024, bwd_hw_b + (l * 2 + 1) * 1024,
        nullptr, nullptr, out + (size_t)l * M_ * N_, 1);
  }
}